// Round 3
// baseline (543.262 us; speedup 1.0000x reference)
//
#include <hip/hip_runtime.h>
#include <hip/hip_bf16.h>

// ---------------------------------------------------------------------------
// Transformer encoder layer (post-norm), bf16 MFMA implementation.
// D=1024, H=16, HD=64, FF=4096, B=4, S=2048 -> 8192 tokens.
//
// Round 9 (= round 8 with launch-bounds fix):
//  - gemm256_bf16_kernel: BM=BN=256, BK=64 (two 32-col k-halves), 8 waves
//    (2Mx4N), 4-slot LDS rotation (128 KiB), 8 phases per 2 K-tiles.
//    Counted vmcnt(4) once per K-tile (never 0 in main loop); raw
//    s_barrier pairs per phase; setprio(1) around each 16-MFMA cluster.
//  - FIX vs round 8: __launch_bounds__(512, 2) not (512, 1). A 512-thread
//    block needs 2 waves/EU co-resident; min-waves=1 lets regalloc exceed
//    256 VGPRs -> unlaunchable kernel (hipErrorOutOfResources, container
//    death). (512,2) caps VGPR at 256.
//  - Also: explicit lgkmcnt(0)+sched_barrier after the pre-MFMA barrier,
//    matching the verified 8-phase template.
//  - Wout GEMM (N=1024, tail-bound) stays on the old 128x128 kernel.
//  - attention unchanged from round 7 (in-register P via permlane swaps).
// ---------------------------------------------------------------------------

typedef __attribute__((ext_vector_type(8))) short          short8;
typedef __attribute__((ext_vector_type(8))) unsigned short ushort8;
typedef __attribute__((ext_vector_type(4))) float          f32x4;
typedef __attribute__((ext_vector_type(2))) unsigned int   uivec2;

__device__ __forceinline__ unsigned short f2bf(float f) {
    union { float f; unsigned int u; } v; v.f = f;
    unsigned int u = v.u;
    unsigned int r = (u + 0x7fffu + ((u >> 16) & 1u)) >> 16;
    return (unsigned short)r;
}

__device__ __forceinline__ float bf2f(unsigned short u) {
    union { unsigned int u; float f; } v; v.u = ((unsigned int)u) << 16;
    return v.f;
}

// truncate-pack two f32 -> (bf16(hi)<<16)|bf16(lo)
__device__ __forceinline__ unsigned int pack_bf16_trunc(float lo, float hi) {
    union { float f; unsigned int u; } a, b; a.f = lo; b.f = hi;
    return __builtin_amdgcn_perm(b.u, a.u, 0x07060302u);  // {b.hi16, a.hi16}
}

// async global->LDS, 16 B per lane. LDS dest = wave-uniform base + lane*16.
__device__ __forceinline__ void async_load16(const void* g, void* l) {
    __builtin_amdgcn_global_load_lds(
        (const __attribute__((address_space(1))) void*)(unsigned long long)g,
        (__attribute__((address_space(3))) void*)(unsigned long long)l,
        16, 0, 0);
}

// ---------------------------------------------------------------------------
// cast f32 -> bf16, 4 elems/thread
__global__ __launch_bounds__(256) void cast_bf16_kernel(
    const float* __restrict__ x, unsigned short* __restrict__ y) {
    size_t i = ((size_t)blockIdx.x * 256 + threadIdx.x) * 4;
    float4 v = *(const float4*)(x + i);
    ushort4 o; o.x = f2bf(v.x); o.y = f2bf(v.y); o.z = f2bf(v.z); o.w = f2bf(v.w);
    *(ushort4*)(y + i) = o;
}

// ---------------------------------------------------------------------------
// W [K,N] f32 row-major  ->  Wt [N,K] bf16 row-major
__global__ __launch_bounds__(256) void transpose_cast_kernel(
    const float* __restrict__ W, unsigned short* __restrict__ Wt, int K, int N) {
    __shared__ float tile[32][33];
    int n0 = blockIdx.x * 32, k0 = blockIdx.y * 32;
    int tx = threadIdx.x & 31, ty = threadIdx.x >> 5;
#pragma unroll
    for (int i = 0; i < 32; i += 8)
        tile[ty + i][tx] = W[(size_t)(k0 + ty + i) * N + n0 + tx];
    __syncthreads();
#pragma unroll
    for (int i = 0; i < 32; i += 8)
        Wt[(size_t)(n0 + ty + i) * K + k0 + tx] = f2bf(tile[tx][ty + i]);
}

// ---------------------------------------------------------------------------
// OLD 128x128 GEMM (kept for Wout). MODE 0: bf16 out; 1: outF = acc + resF.
template <int MODE>
__global__ __launch_bounds__(256) void gemm_bf16_kernel(
    const unsigned short* __restrict__ A, const unsigned short* __restrict__ Bt,
    int M, int N, int K, int Kstride,
    float* __restrict__ outF, unsigned short* __restrict__ outB,
    const float* __restrict__ bias,
    const float* __restrict__ resF, const unsigned short* __restrict__ resB,
    unsigned short* __restrict__ vtB) {
    __shared__ unsigned short As[2][128 * 32];
    __shared__ unsigned short Bs[2][128 * 32];

    const int t = threadIdx.x;
    const int m0 = blockIdx.x * 128, n0 = blockIdx.y * 128;
    const int koff = blockIdx.z * K;
    const int wid = t >> 6, lane = t & 63;
    const int wm = wid >> 1, wn = wid & 1;
    const int lr = lane & 15, quad = lane >> 4;

    const int srow = lane >> 2;                       // 0..15
    const int sch  = ((lane & 3) ^ (srow & 3)) * 8;   // swizzled logical chunk
    const unsigned short* Ag =
        A  + (size_t)(m0 + wid * 32 + srow) * Kstride + koff + sch;
    const unsigned short* Bg =
        Bt + (size_t)(n0 + wid * 32 + srow) * Kstride + koff + sch;
    const int wofs = (wid * 32) * 32;
    const size_t rstep = (size_t)16 * Kstride;

    const int axs = ((quad ^ (lr & 3))) * 8;          // phys chunk for reads
    f32x4 acc[4][4] = {};

    const int nK = K >> 5;
    async_load16(Ag,         &As[0][wofs]);
    async_load16(Ag + rstep, &As[0][wofs + 16 * 32]);
    async_load16(Bg,         &Bs[0][wofs]);
    async_load16(Bg + rstep, &Bs[0][wofs + 16 * 32]);

    for (int kt = 0; kt < nK; kt++) {
        const int cur = kt & 1, nxt = cur ^ 1;
        __syncthreads();
        if (kt + 1 < nK) {
            const int k1 = (kt + 1) * 32;
            async_load16(Ag + k1,         &As[nxt][wofs]);
            async_load16(Ag + k1 + rstep, &As[nxt][wofs + 16 * 32]);
            async_load16(Bg + k1,         &Bs[nxt][wofs]);
            async_load16(Bg + k1 + rstep, &Bs[nxt][wofs + 16 * 32]);
        }

        short8 af[4], bfr[4];
#pragma unroll
        for (int i = 0; i < 4; i++) {
            af[i]  = *(const short8*)&As[cur][(wm * 64 + i * 16 + lr) * 32 + axs];
            bfr[i] = *(const short8*)&Bs[cur][(wn * 64 + i * 16 + lr) * 32 + axs];
        }
#pragma unroll
        for (int mi = 0; mi < 4; mi++)
#pragma unroll
            for (int ni = 0; ni < 4; ni++)
                acc[mi][ni] = __builtin_amdgcn_mfma_f32_16x16x32_bf16(
                    af[mi], bfr[ni], acc[mi][ni], 0, 0, 0);
    }

#pragma unroll
    for (int mi = 0; mi < 4; mi++)
#pragma unroll
        for (int ni = 0; ni < 4; ni++) {
            const int col  = n0 + wn * 64 + ni * 16 + lr;
            const int row0 = m0 + wm * 64 + mi * 16 + quad * 4;
#pragma unroll
            for (int r = 0; r < 4; r++) {
                size_t idx = (size_t)(row0 + r) * N + col;
                float v = acc[mi][ni][r];
                if (MODE == 0) {
                    outB[idx] = f2bf(v);
                } else if (MODE == 1) {
                    outF[idx] = v + resF[idx];
                }
            }
        }
}

// ---------------------------------------------------------------------------
// NEW 256x256 8-phase GEMM. C[M,N] = A[M,K(slice)] @ B[K,N], Bt = B^T.
// 512 threads = 8 waves (2M x 4N); per-wave C = 128x64 (8 Mfrag x 4 Nfrag).
// BK=64 as two 32-col k-halves; LDS = 4 rotating slots per matrix
// ([256 rows][32 cols] bf16, chunk-XOR swizzled), 128 KiB total.
// Slot-safety: a slot's DMA is issued only after the barrier that retired
// its readers; each wave's vmcnt(4) at phase 3 completes exactly the two
// units the NEXT K-tile reads, before the publishing barrier.
#define GBAR() do { __builtin_amdgcn_sched_barrier(0); \
                    __builtin_amdgcn_s_barrier();      \
                    __builtin_amdgcn_sched_barrier(0); } while (0)

template <int MODE>
__global__ __launch_bounds__(512, 2) void gemm256_bf16_kernel(
    const unsigned short* __restrict__ A, const unsigned short* __restrict__ Bt,
    int M, int N, int K, int Kstride,
    float* __restrict__ outF, unsigned short* __restrict__ outB,
    const float* __restrict__ bias,
    const float* __restrict__ resF, const unsigned short* __restrict__ resB,
    unsigned short* __restrict__ vtB) {
    __shared__ unsigned short Alds[4][256 * 32];   // 4 k-half slots, 16 KiB each
    __shared__ unsigned short Blds[4][256 * 32];

    const int t = threadIdx.x;
    const int wid = t >> 6, lane = t & 63;
    const int wm = wid >> 2, wn = wid & 3;         // 2 x 4 wave grid
    const int lr = lane & 15, quad = lane >> 4;
    const int m0 = blockIdx.x * 256, n0 = blockIdx.y * 256;
    const int koff = blockIdx.z * K;

    // staging: wave w covers rows [32w, 32w+32) of each unit; lane l writes
    // row 32w + j*16 + (l>>2), phys chunk l&3 (linear LDS dest).
    const int srow = wid * 32 + (lane >> 2);
    const int sch  = ((lane & 3) ^ (srow & 3)) * 8;   // fetch-side swizzle
    const unsigned short* Ag = A  + (size_t)(m0 + srow) * Kstride + koff + sch;
    const unsigned short* Bg = Bt + (size_t)(n0 + srow) * Kstride + koff + sch;
    const size_t rstep = (size_t)16 * Kstride;
    unsigned short* AdstW = &Alds[0][(wid * 32) * 32];  // + slot*256*32
    unsigned short* BdstW = &Blds[0][(wid * 32) * 32];

    const int axs = (quad ^ (lr & 3)) * 8;            // phys chunk for reads

    f32x4 acc[8][4] = {};
    short8 bfr[4];

    const int T = K >> 6;        // K-tiles (BK=64); k-halves = 2T
    const int Tm2 = T - 2, Tm3 = T - 3;

#define STAGE_A(GP) do { int s_ = (GP) & 3;                                   \
        const unsigned short* g_ = Ag + (GP) * 32;                            \
        async_load16(g_,         AdstW + s_ * 256 * 32);                      \
        async_load16(g_ + rstep, AdstW + s_ * 256 * 32 + 16 * 32); } while (0)
#define STAGE_B(GP) do { int s_ = (GP) & 3;                                   \
        const unsigned short* g_ = Bg + (GP) * 32;                            \
        async_load16(g_,         BdstW + s_ * 256 * 32);                      \
        async_load16(g_ + rstep, BdstW + s_ * 256 * 32 + 16 * 32); } while (0)

    // prologue: units for k-halves 0,1,2 (12 loads); vmcnt(4) completes
    // units 0 and 1 (8 loads) -> slots 0,1 ready for tile 0.
    STAGE_A(0); STAGE_B(0);
    STAGE_A(1); STAGE_B(1);
    STAGE_A(2); STAGE_B(2);
    asm volatile("s_waitcnt vmcnt(4)" ::: "memory");
    GBAR();

#define GPHASE(SLOT, MB, LOADB)                                               \
    {                                                                         \
        short8 af_[4];                                                        \
        _Pragma("unroll")                                                     \
        for (int i_ = 0; i_ < 4; i_++)                                        \
            af_[i_] = *(const short8*)                                        \
                &Alds[SLOT][(wm * 128 + ((MB) + i_) * 16 + lr) * 32 + axs];   \
        if (LOADB) {                                                          \
            _Pragma("unroll")                                                 \
            for (int i_ = 0; i_ < 4; i_++)                                    \
                bfr[i_] = *(const short8*)                                    \
                    &Blds[SLOT][(wn * 64 + i_ * 16 + lr) * 32 + axs];         \
        }

#define GPHASE_END(MB)                                                        \
        GBAR();                                                               \
        asm volatile("s_waitcnt lgkmcnt(0)" ::: "memory");                    \
        __builtin_amdgcn_sched_barrier(0);                                    \
        __builtin_amdgcn_s_setprio(1);                                        \
        _Pragma("unroll")                                                     \
        for (int mi_ = 0; mi_ < 4; mi_++)                                     \
            _Pragma("unroll")                                                 \
            for (int ni_ = 0; ni_ < 4; ni_++)                                 \
                acc[(MB) + mi_][ni_] = __builtin_amdgcn_mfma_f32_16x16x32_bf16( \
                    af_[mi_], bfr[ni_], acc[(MB) + mi_][ni_], 0, 0, 0);       \
        __builtin_amdgcn_s_setprio(0);                                        \
        GBAR();                                                               \
    }

    for (int t2 = 0; t2 < T; t2++) {
        const int s0 = (2 * t2) & 3, s1 = (2 * t2 + 1) & 3;
        const int gA = 2 * t2 + 3, gB = 2 * t2 + 4;

        // phase 0: kh0, M-frags 0-3, load B-frags; issue A(g+3)
        GPHASE(s0, 0, 1)
            if (t2 <= Tm2) STAGE_A(gA);
        GPHASE_END(0)
        // phase 1: kh0, M-frags 4-7, reuse B; issue B(g+3)
        GPHASE(s0, 4, 0)
            if (t2 <= Tm2) STAGE_B(gA);
        GPHASE_END(4)
        // phase 2: kh1, M-frags 0-3, load B; issue A(g+4)
        GPHASE(s1, 0, 1)
            if (t2 <= Tm3) STAGE_A(gB);
        GPHASE_END(0)
        // phase 3: kh1, M-frags 4-7, reuse B; issue B(g+4); K-tile wait
        GPHASE(s1, 4, 0)
            if (t2 <= Tm3) STAGE_B(gB);
            if (t2 == Tm2) {
                asm volatile("s_waitcnt vmcnt(0)" ::: "memory");
            } else if (t2 < Tm2) {
                asm volatile("s_waitcnt vmcnt(4)" ::: "memory");
            }
        GPHASE_END(4)
    }

#undef GPHASE
#undef GPHASE_END
#undef STAGE_A
#undef STAGE_B

    // epilogue
    const float QSC = 0.18033688011112042f;  // (1/8) * log2(e)
    float* pOut = (MODE == 5) ? outF + (size_t)blockIdx.z * M * N : outF;
#pragma unroll
    for (int mi = 0; mi < 8; mi++)
#pragma unroll
        for (int ni = 0; ni < 4; ni++) {
            const int col  = n0 + wn * 64 + ni * 16 + lr;
            const int row0 = m0 + wm * 128 + mi * 16 + quad * 4;
            if (MODE == 4 && col >= 2048) {
                // V portion: store transposed Vt[b][c][s], 4 consecutive s
                int bb = row0 >> 11, ss = row0 & 2047, c = col - 2048;
                ushort4 ov;
                ov.x = f2bf(acc[mi][ni][0]); ov.y = f2bf(acc[mi][ni][1]);
                ov.z = f2bf(acc[mi][ni][2]); ov.w = f2bf(acc[mi][ni][3]);
                *(ushort4*)&vtB[((size_t)bb * 1024 + c) * 2048 + ss] = ov;
            } else {
#pragma unroll
                for (int r = 0; r < 4; r++) {
                    size_t idx = (size_t)(row0 + r) * N + col;
                    float v = acc[mi][ni][r];
                    if (MODE == 4) {
                        outB[idx] = f2bf(col < 1024 ? v * QSC : v);
                    } else if (MODE == 2) {
                        v += bias[col];
                        outB[idx] = f2bf(v > 0.f ? v : 0.f);
                    } else if (MODE == 5) {
                        pOut[idx] = v;
                    }
                }
            }
        }
}

// ---------------------------------------------------------------------------
// Flash attention, S^T formulation, no online max (scores bounded).
// P kept fully in registers via permlane32_swap + permlane16_swap (round 7).
__global__ __launch_bounds__(256) void attention_kernel(
    const unsigned short* __restrict__ qkv, const unsigned short* __restrict__ Vt,
    unsigned short* __restrict__ ctx) {
    __shared__ unsigned short Kbuf[2][64 * 64];   // [key][hd], chunk-swizzled
    __shared__ unsigned short Vbuf[2][64 * 64];   // [hd][key], chunk-swizzled

    const int qt = blockIdx.x, h = blockIdx.y, b = blockIdx.z;
    const int t = threadIdx.x, wid = t >> 6, lane = t & 63;
    const int lr = lane & 15, quad = lane >> 4;
    const int q0 = qt * 64 + wid * 16;

    size_t qbase = ((size_t)(b * 2048 + q0 + lr)) * 3072 + h * 64;
    short8 qf0 = *(const short8*)(qkv + qbase + quad * 8);
    short8 qf1 = *(const short8*)(qkv + qbase + 32 + quad * 8);

    const int srow = wid * 8 + (lane >> 3);            // 0..31
    const int sch  = ((lane & 7) ^ (srow & 7)) * 8;    // fetch-side swizzle
    const unsigned short* Kg =
        qkv + (size_t)b * 2048 * 3072 + 1024 + h * 64 + (size_t)srow * 3072 + sch;
    const unsigned short* Vg =
        Vt + ((size_t)b * 1024 + h * 64 + srow) * 2048 + sch;
    unsigned short* KsB = (unsigned short*)&Kbuf[0][(wid * 8) * 64];
    unsigned short* VsB = (unsigned short*)&Vbuf[0][(wid * 8) * 64];
    const int bufstep = 64 * 64;

    short8 ones;
#pragma unroll
    for (int i = 0; i < 8; i++) ones[i] = (short)0x3F80;  // bf16 1.0

    f32x4 o[4] = {};
    f32x4 lacc = {};

#pragma unroll
    for (int half = 0; half < 2; half++) {
        async_load16(Kg + (size_t)(half * 32) * 3072, KsB + half * 32 * 64);
        async_load16(Vg + (size_t)(half * 32) * 2048, VsB + half * 32 * 64);
    }

    const int swz = lr & 7;

    for (int kt = 0; kt < 32; kt++) {
        const int cur = kt & 1, nxt = cur ^ 1;
        __syncthreads();
        if (kt + 1 < 32) {
#pragma unroll
            for (int half = 0; half < 2; half++) {
                async_load16(Kg + (size_t)((kt + 1) * 64 + half * 32) * 3072,
                             KsB + nxt * bufstep + half * 32 * 64);
                async_load16(Vg + (size_t)(half * 32) * 2048 + (kt + 1) * 64,
                             VsB + nxt * bufstep + half * 32 * 64);
            }
        }

        const unsigned short* Kc = &Kbuf[cur][0];
        const unsigned short* Vc = &Vbuf[cur][0];

        f32x4 s[4] = {};
#pragma unroll
        for (int nt = 0; nt < 4; nt++) {
            const unsigned short* krow = Kc + (nt * 16 + lr) * 64;
            short8 kf0 = *(const short8*)(krow + (quad ^ swz) * 8);
            short8 kf1 = *(const short8*)(krow + ((quad + 4) ^ swz) * 8);
            s[nt] = __builtin_amdgcn_mfma_f32_16x16x32_bf16(kf0, qf0, s[nt], 0, 0, 0);
            s[nt] = __builtin_amdgcn_mfma_f32_16x16x32_bf16(kf1, qf1, s[nt], 0, 0, 0);
        }

        // exp2 + pack into bf16x2 words; aw = keys (.,+1), bw = keys (+2,+3)
        unsigned int aw[4], bw[4];
#pragma unroll
        for (int nt = 0; nt < 4; nt++) {
            float p0 = __builtin_amdgcn_exp2f(s[nt][0]);
            float p1 = __builtin_amdgcn_exp2f(s[nt][1]);
            float p2 = __builtin_amdgcn_exp2f(s[nt][2]);
            float p3 = __builtin_amdgcn_exp2f(s[nt][3]);
            aw[nt] = pack_bf16_trunc(p0, p1);
            bw[nt] = pack_bf16_trunc(p2, p3);
        }

        // cross-quad redistribution, P stays in VGPRs
        uivec2 rA = __builtin_amdgcn_permlane32_swap(aw[0], aw[1], false, false);
        uivec2 sA = __builtin_amdgcn_permlane32_swap(aw[2], aw[3], false, false);
        uivec2 rB = __builtin_amdgcn_permlane32_swap(bw[0], bw[1], false, false);
        uivec2 sB = __builtin_amdgcn_permlane32_swap(bw[2], bw[3], false, false);
        uivec2 tA = __builtin_amdgcn_permlane16_swap(rA.x, rA.y, false, false);
        uivec2 uA = __builtin_amdgcn_permlane16_swap(sA.x, sA.y, false, false);
        uivec2 tB = __builtin_amdgcn_permlane16_swap(rB.x, rB.y, false, false);
        uivec2 uB = __builtin_amdgcn_permlane16_swap(sB.x, sB.y, false, false);

        union { unsigned int w[4]; short8 v; } P0, P1;
        P0.w[0] = tA.x; P0.w[1] = tB.x; P0.w[2] = tA.y; P0.w[3] = tB.y;
        P1.w[0] = uA.x; P1.w[1] = uB.x; P1.w[2] = uA.y; P1.w[3] = uB.y;
        short8 pf0 = P0.v;
        short8 pf1 = P1.v;

#pragma unroll
        for (int nt = 0; nt < 4; nt++) {
            const unsigned short* vrow = Vc + (nt * 16 + lr) * 64;
            short8 vf0 = *(const short8*)(vrow + (quad ^ swz) * 8);
            short8 vf1 = *(const short8*)(vrow + ((quad + 4) ^ swz) * 8);
            o[nt] = __builtin_amdgcn_mfma_f32_16x16x32_bf16(pf0, vf0, o[nt], 0, 0, 0);
            o[nt] = __builtin_amdgcn_mfma_f32_16x16x32_bf16(pf1, vf1, o[nt], 0, 0, 0);
        }
        lacc = __builtin_amdgcn_mfma_f32_16x16x32_bf16(pf0, ones, lacc, 0, 0, 0);
        lacc = __builtin_amdgcn_mfma_f32_16x16x32_bf16(pf1, ones, lacc, 0, 0, 0);
    }

#pragma unroll
    for (int r = 0; r < 4; r++) {
        float li = 1.f / lacc[r];
        int q = qt * 64 + wid * 16 + quad * 4 + r;
#pragma unroll
        for (int nt = 0; nt < 4; nt++)
            ctx[((size_t)(b * 2048 + q)) * 1024 + h * 64 + nt * 16 + lr] =
                f2bf(o[nt][r] * li);
    }
}

// ---------------------------------------------------------------------------
// LayerNorm over rows of 1024. OUTMODE 0: f32 out; 1: bf16 out.
template <int OUTMODE>
__global__ __launch_bounds__(256) void layernorm_kernel(
    const float* __restrict__ x, const float* __restrict__ g,
    const float* __restrict__ be, float* __restrict__ yF,
    unsigned short* __restrict__ yB) {
    const int row = blockIdx.x, t = threadIdx.x;
    const float* xr = x + (size_t)row * 1024;
    float4 v = *(const float4*)(xr + t * 4);
    float s  = v.x + v.y + v.z + v.w;
    float sq = v.x * v.x + v.y * v.y + v.z * v.z + v.w * v.w;
#pragma unroll
    for (int d = 1; d < 64; d <<= 1) {
        s  += __shfl_xor(s, d, 64);
        sq += __shfl_xor(sq, d, 64);
    }
    __shared__ float sh[8];
    int wid = t >> 6, lane = t & 63;
    if (lane == 0) { sh[wid] = s; sh[4 + wid] = sq; }
    __syncthreads();
    s  = sh[0] + sh[1] + sh[2] + sh[3];
    sq = sh[4] + sh[5] + sh[6] + sh[7];
    float mu  = s * (1.f / 1024.f);
    float var = sq * (1.f / 1024.f) - mu * mu;
    float rstd = rsqrtf(var + 1e-5f);
    float4 gv = *(const float4*)(g + t * 4);
    float4 bv = *(const float4*)(be + t * 4);
    float4 y;
    y.x = (v.x - mu) * rstd * gv.x + bv.x;
    y.y = (v.y - mu) * rstd * gv.y + bv.y;
    y.z = (v.z - mu) * rstd * gv.z + bv.z;
    y.w = (v.w - mu) * rstd * gv.w + bv.w;
    if (OUTMODE == 0) {
        *(float4*)(yF + (size_t)row * 1024 + t * 4) = y;
    } else {
        ushort4 o;
        o.x = f2bf(y.x); o.y = f2bf(y.y); o.z = f2bf(y.z); o.w = f2bf(y.w);
        *(ushort4*)(yB + (size_t)row * 1024 + t * 4) = o;
    }
}

// ---------------------------------------------------------------------------
// LN2 with fused split-K reduce: x = p0 + p1 + bias + bf16(res); f32 out.
__global__ __launch_bounds__(256) void layernorm_sum2_kernel(
    const float* __restrict__ p0, const float* __restrict__ p1,
    const float* __restrict__ bias, const unsigned short* __restrict__ res,
    const float* __restrict__ g, const float* __restrict__ be,
    float* __restrict__ out) {
    const int row = blockIdx.x, t = threadIdx.x;
    const size_t base = (size_t)row * 1024 + t * 4;
    float4 a = *(const float4*)(p0 + base);
    float4 b = *(const float4*)(p1 + base);
    float4 bi = *(const float4*)(bias + t * 4);
    ushort4 rb = *(const ushort4*)(res + base);
    float4 v;
    v.x = a.x + b.x + bi.x + bf2f(rb.x);
    v.y = a.y + b.y + bi.y + bf2f(rb.y);
    v.z = a.z + b.z + bi.z + bf2f(rb.z);
    v.w = a.w + b.w + bi.w + bf2f(rb.w);
    float s  = v.x + v.y + v.z + v.w;
    float sq = v.x * v.x + v.y * v.y + v.z * v.z + v.w * v.w;
#pragma unroll
    for (int d = 1; d < 64; d <<= 1) {
        s  += __shfl_xor(s, d, 64);
        sq += __shfl_xor(sq, d, 64);
    }
    __shared__ float sh[8];
    int wid = t >> 6, lane = t & 63;
    if (lane == 0) { sh[wid] = s; sh[4 + wid] = sq; }
    __syncthreads();
    s  = sh[0] + sh[1] + sh[2] + sh[3];
    sq = sh[4] + sh[5] + sh[6] + sh[7];
    float mu  = s * (1.f / 1024.f);
    float var = sq * (1.f / 1024.f) - mu * mu;
    float rstd = rsqrtf(var + 1e-5f);
    float4 gv = *(const float4*)(g + t * 4);
    float4 bv = *(const float4*)(be + t * 4);
    float4 y;
    y.x = (v.x - mu) * rstd * gv.x + bv.x;
    y.y = (v.y - mu) * rstd * gv.y + bv.y;
    y.z = (v.z - mu) * rstd * gv.z + bv.z;
    y.w = (v.w - mu) * rstd * gv.w + bv.w;
    *(float4*)(out + base) = y;
}

// ---------------------------------------------------------------------------
extern "C" void kernel_launch(void* const* d_in, const int* in_sizes, int n_in,
                              void* d_out, int out_size, void* d_ws, size_t ws_size,
                              hipStream_t stream) {
    const float* src  = (const float*)d_in[0];
    const float* Wqkv = (const float*)d_in[1];
    const float* Wout = (const float*)d_in[2];
    const float* W1   = (const float*)d_in[3];
    const float* b1   = (const float*)d_in[4];
    const float* W2   = (const float*)d_in[5];
    const float* b2   = (const float*)d_in[6];
    const float* g1   = (const float*)d_in[7];
    const float* be1  = (const float*)d_in[8];
    const float* g2   = (const float*)d_in[9];
    const float* be2  = (const float*)d_in[10];
    float* out = (float*)d_out;

    const size_t NT = 8192;  // tokens = 4*2048
    char* ws = (char*)d_ws;
    unsigned short* src_bf = (unsigned short*)ws; ws += NT * 1024 * 2;
    unsigned short* Wqkv_t = (unsigned short*)ws; ws += (size_t)3072 * 1024 * 2;
    unsigned short* Wout_t = (unsigned short*)ws; ws += (size_t)1024 * 1024 * 2;
    unsigned short* W1_t   = (unsigned short*)ws; ws += (size_t)4096 * 1024 * 2;
    unsigned short* W2_t   = (unsigned short*)ws; ws += (size_t)1024 * 4096 * 2;
    unsigned short* qkv_bf = (unsigned short*)ws; ws += NT * 3072 * 2;  // 48 MB
    unsigned short* ctx_bf = (unsigned short*)ws; ws += NT * 1024 * 2;  // 16 MB
    float*          x1     = (float*)ws;          ws += NT * 1024 * 4;  // 32 MB
    unsigned short* y1_bf  = (unsigned short*)ws; ws += NT * 1024 * 2;
    unsigned short* h_bf   = (unsigned short*)ws; ws += NT * 4096 * 2;
    // aliases over dead buffers:
    unsigned short* Vt = h_bf;      // Vt dead before GEMM3 writes h_bf
    // Split-K partials: 2 x 32 MB CONTIGUOUS in qkv_bf..ctx_bf (64 MB).
    float* part = (float*)qkv_bf;   // z=0 at +0, z=1 at +NT*1024 floats

    // pre-pass: casts + weight transposes
    cast_bf16_kernel<<<8192, 256, 0, stream>>>(src, src_bf);
    transpose_cast_kernel<<<dim3(96, 32), 256, 0, stream>>>(Wqkv, Wqkv_t, 1024, 3072);
    transpose_cast_kernel<<<dim3(32, 32), 256, 0, stream>>>(Wout, Wout_t, 1024, 1024);
    transpose_cast_kernel<<<dim3(128, 32), 256, 0, stream>>>(W1, W1_t, 1024, 4096);
    transpose_cast_kernel<<<dim3(32, 128), 256, 0, stream>>>(W2, W2_t, 4096, 1024);

    // qkv = src @ Wqkv  (Q scaled -> qkv_bf; K -> qkv_bf; V -> Vt transposed)
    gemm256_bf16_kernel<4><<<dim3(32, 12), 512, 0, stream>>>(
        src_bf, Wqkv_t, 8192, 3072, 1024, 1024,
        nullptr, qkv_bf, nullptr, nullptr, nullptr, Vt);
    // attention
    attention_kernel<<<dim3(32, 16, 4), 256, 0, stream>>>(qkv_bf, Vt, ctx_bf);
    // x1 = ctx @ Wout + src   (old 128x128 kernel: N=1024 tail-bound shape)
    gemm_bf16_kernel<1><<<dim3(64, 8), 256, 0, stream>>>(
        ctx_bf, Wout_t, 8192, 1024, 1024, 1024,
        x1, nullptr, nullptr, src, nullptr, nullptr);
    // y1 = LN1(x1)
    layernorm_kernel<1><<<8192, 256, 0, stream>>>(x1, g1, be1, nullptr, y1_bf);
    // h = relu(y1 @ W1 + b1)
    gemm256_bf16_kernel<2><<<dim3(32, 16), 512, 0, stream>>>(
        y1_bf, W1_t, 8192, 4096, 1024, 1024,
        nullptr, h_bf, b1, nullptr, nullptr, nullptr);
    // split-K x2: part[z] = h @ W2[zK:(z+1)K, :]   (z = blockIdx.z)
    gemm256_bf16_kernel<5><<<dim3(32, 4, 2), 512, 0, stream>>>(
        h_bf, W2_t, 8192, 1024, 2048, 4096,
        part, nullptr, nullptr, nullptr, nullptr, nullptr);
    // out = LN2(part0 + part1 + b2 + y1)
    layernorm_sum2_kernel<<<8192, 256, 0, stream>>>(
        part, part + NT * 1024, b2, y1_bf, g2, be2, out);
}

// Round 4
// 542.783 us; speedup vs baseline: 1.0009x; 1.0009x over previous
//
#include <hip/hip_runtime.h>
#include <hip/hip_bf16.h>

// ---------------------------------------------------------------------------
// Transformer encoder layer (post-norm), bf16 MFMA implementation.
// D=1024, H=16, HD=64, FF=4096, B=4, S=2048 -> 8192 tokens.
//
// Round 10 (gemm256 v2 — conflict-free LDS geometry + burst prefetch):
//  - Round-2's gemm256 measured MfmaUtil 17.9% with 4.7M bank conflicts:
//    64B LDS rows give a structural 2x LDS-read penalty (16-lane groups,
//    only 4 chunks/row). v2 uses the attention kernel's proven geometry:
//    128B rows ([256][64] bf16 per K-tile), 8-chunk XOR swizzle -> 0
//    conflicts (attention measures 0 with this exact pattern).
//  - 2 buffers x (A 32KB + B 32KB) = 128KB. Burst-stage tile t+2 (8
//    global_load_lds per wave) after the barrier that retires buf[t&1]'s
//    readers; publish-wait vmcnt(8) at iter top (vmcnt(0) only last iter).
//    4-phase (~600-800cy) prefetch lead.
//  - Fencing reduced to the verified template: per phase only
//    {s_barrier; lgkmcnt(0); sched_barrier(0); setprio(1); 16 MFMA;
//    setprio(0); s_barrier}. (Round-2 had 5 sched fences/phase = the
//    documented m141 order-pinning regression.)
//  - XCD-chunked block swizzle (grids 384/512/128, all %8==0).
//  - Wout GEMM stays on the old 128x128 kernel; attention unchanged.
// ---------------------------------------------------------------------------

typedef __attribute__((ext_vector_type(8))) short          short8;
typedef __attribute__((ext_vector_type(8))) unsigned short ushort8;
typedef __attribute__((ext_vector_type(4))) float          f32x4;
typedef __attribute__((ext_vector_type(2))) unsigned int   uivec2;

__device__ __forceinline__ unsigned short f2bf(float f) {
    union { float f; unsigned int u; } v; v.f = f;
    unsigned int u = v.u;
    unsigned int r = (u + 0x7fffu + ((u >> 16) & 1u)) >> 16;
    return (unsigned short)r;
}

__device__ __forceinline__ float bf2f(unsigned short u) {
    union { unsigned int u; float f; } v; v.u = ((unsigned int)u) << 16;
    return v.f;
}

// truncate-pack two f32 -> (bf16(hi)<<16)|bf16(lo)
__device__ __forceinline__ unsigned int pack_bf16_trunc(float lo, float hi) {
    union { float f; unsigned int u; } a, b; a.f = lo; b.f = hi;
    return __builtin_amdgcn_perm(b.u, a.u, 0x07060302u);  // {b.hi16, a.hi16}
}

// async global->LDS, 16 B per lane. LDS dest = wave-uniform base + lane*16.
__device__ __forceinline__ void async_load16(const void* g, void* l) {
    __builtin_amdgcn_global_load_lds(
        (const __attribute__((address_space(1))) void*)(unsigned long long)g,
        (__attribute__((address_space(3))) void*)(unsigned long long)l,
        16, 0, 0);
}

// ---------------------------------------------------------------------------
// cast f32 -> bf16, 4 elems/thread
__global__ __launch_bounds__(256) void cast_bf16_kernel(
    const float* __restrict__ x, unsigned short* __restrict__ y) {
    size_t i = ((size_t)blockIdx.x * 256 + threadIdx.x) * 4;
    float4 v = *(const float4*)(x + i);
    ushort4 o; o.x = f2bf(v.x); o.y = f2bf(v.y); o.z = f2bf(v.z); o.w = f2bf(v.w);
    *(ushort4*)(y + i) = o;
}

// ---------------------------------------------------------------------------
// W [K,N] f32 row-major  ->  Wt [N,K] bf16 row-major
__global__ __launch_bounds__(256) void transpose_cast_kernel(
    const float* __restrict__ W, unsigned short* __restrict__ Wt, int K, int N) {
    __shared__ float tile[32][33];
    int n0 = blockIdx.x * 32, k0 = blockIdx.y * 32;
    int tx = threadIdx.x & 31, ty = threadIdx.x >> 5;
#pragma unroll
    for (int i = 0; i < 32; i += 8)
        tile[ty + i][tx] = W[(size_t)(k0 + ty + i) * N + n0 + tx];
    __syncthreads();
#pragma unroll
    for (int i = 0; i < 32; i += 8)
        Wt[(size_t)(n0 + ty + i) * K + k0 + tx] = f2bf(tile[tx][ty + i]);
}

// ---------------------------------------------------------------------------
// OLD 128x128 GEMM (kept for Wout). MODE 0: bf16 out; 1: outF = acc + resF.
template <int MODE>
__global__ __launch_bounds__(256) void gemm_bf16_kernel(
    const unsigned short* __restrict__ A, const unsigned short* __restrict__ Bt,
    int M, int N, int K, int Kstride,
    float* __restrict__ outF, unsigned short* __restrict__ outB,
    const float* __restrict__ bias,
    const float* __restrict__ resF, const unsigned short* __restrict__ resB,
    unsigned short* __restrict__ vtB) {
    __shared__ unsigned short As[2][128 * 32];
    __shared__ unsigned short Bs[2][128 * 32];

    const int t = threadIdx.x;
    const int m0 = blockIdx.x * 128, n0 = blockIdx.y * 128;
    const int koff = blockIdx.z * K;
    const int wid = t >> 6, lane = t & 63;
    const int wm = wid >> 1, wn = wid & 1;
    const int lr = lane & 15, quad = lane >> 4;

    const int srow = lane >> 2;                       // 0..15
    const int sch  = ((lane & 3) ^ (srow & 3)) * 8;   // swizzled logical chunk
    const unsigned short* Ag =
        A  + (size_t)(m0 + wid * 32 + srow) * Kstride + koff + sch;
    const unsigned short* Bg =
        Bt + (size_t)(n0 + wid * 32 + srow) * Kstride + koff + sch;
    const int wofs = (wid * 32) * 32;
    const size_t rstep = (size_t)16 * Kstride;

    const int axs = ((quad ^ (lr & 3))) * 8;          // phys chunk for reads
    f32x4 acc[4][4] = {};

    const int nK = K >> 5;
    async_load16(Ag,         &As[0][wofs]);
    async_load16(Ag + rstep, &As[0][wofs + 16 * 32]);
    async_load16(Bg,         &Bs[0][wofs]);
    async_load16(Bg + rstep, &Bs[0][wofs + 16 * 32]);

    for (int kt = 0; kt < nK; kt++) {
        const int cur = kt & 1, nxt = cur ^ 1;
        __syncthreads();
        if (kt + 1 < nK) {
            const int k1 = (kt + 1) * 32;
            async_load16(Ag + k1,         &As[nxt][wofs]);
            async_load16(Ag + k1 + rstep, &As[nxt][wofs + 16 * 32]);
            async_load16(Bg + k1,         &Bs[nxt][wofs]);
            async_load16(Bg + k1 + rstep, &Bs[nxt][wofs + 16 * 32]);
        }

        short8 af[4], bfr[4];
#pragma unroll
        for (int i = 0; i < 4; i++) {
            af[i]  = *(const short8*)&As[cur][(wm * 64 + i * 16 + lr) * 32 + axs];
            bfr[i] = *(const short8*)&Bs[cur][(wn * 64 + i * 16 + lr) * 32 + axs];
        }
#pragma unroll
        for (int mi = 0; mi < 4; mi++)
#pragma unroll
            for (int ni = 0; ni < 4; ni++)
                acc[mi][ni] = __builtin_amdgcn_mfma_f32_16x16x32_bf16(
                    af[mi], bfr[ni], acc[mi][ni], 0, 0, 0);
    }

#pragma unroll
    for (int mi = 0; mi < 4; mi++)
#pragma unroll
        for (int ni = 0; ni < 4; ni++) {
            const int col  = n0 + wn * 64 + ni * 16 + lr;
            const int row0 = m0 + wm * 64 + mi * 16 + quad * 4;
#pragma unroll
            for (int r = 0; r < 4; r++) {
                size_t idx = (size_t)(row0 + r) * N + col;
                float v = acc[mi][ni][r];
                if (MODE == 0) {
                    outB[idx] = f2bf(v);
                } else if (MODE == 1) {
                    outF[idx] = v + resF[idx];
                }
            }
        }
}

// ---------------------------------------------------------------------------
// gemm256 v2: BM=BN=256, BK=64, 512 thr = 8 waves (2M x 4N), per-wave C =
// 128x64 (8 Mfrag x 4 Nfrag). LDS: 2 buffers x {A,B} x [256 rows][64 cols]
// bf16 (128B rows, chunk-XOR swizzle: phys chunk c of row r holds logical
// c^(r&7)) = 128 KiB. Conflict-free reads (attention-verified pattern).
// 4 phases per K-tile: (kh0,M0-3,+B) (kh0,M4-7) (kh1,M0-3,+B) (kh1,M4-7),
// each {ds_reads; s_barrier; lgkmcnt(0); setprio(1); 16 MFMA; setprio(0);
// s_barrier}. Tile t+2 burst-staged (8 loads/wave) after phase 4's closing
// barrier (all readers of buf[t&1] retired). Publish-wait vmcnt(8) at iter
// top (tile t completes; t+1's 8 loads stay in flight); vmcnt(0) last iter.
// MODE 2: outB = bf16(relu(acc+bias)); MODE 4: qkv split (Q*log2e/8, K,
// V->Vt transposed); MODE 5: f32 partial to outF + z*M*N.
template <int MODE>
__global__ __launch_bounds__(512, 2) void gemm256_bf16_kernel(
    const unsigned short* __restrict__ A, const unsigned short* __restrict__ Bt,
    int M, int N, int K, int Kstride,
    float* __restrict__ outF, unsigned short* __restrict__ outB,
    const float* __restrict__ bias,
    const float* __restrict__ resF, const unsigned short* __restrict__ resB,
    unsigned short* __restrict__ vtB) {
    __shared__ unsigned short Ald[2][256 * 64];   // 32 KiB per buffer
    __shared__ unsigned short Bld[2][256 * 64];

    const int t = threadIdx.x;
    const int wid = t >> 6, lane = t & 63;
    const int wm = wid >> 2, wn = wid & 3;         // 2 x 4 wave grid
    const int lr = lane & 15, quad = lane >> 4;

    // XCD-chunked swizzle (nwg % 8 == 0 for all launches here)
    const int gx = gridDim.x, nwg = gx * gridDim.y;
    const int id = blockIdx.y * gx + blockIdx.x;
    const int nid = (id & 7) * (nwg >> 3) + (id >> 3);
    const int m0 = (nid % gx) * 256, n0 = (nid / gx) * 256;
    const int koff = blockIdx.z * K;

    // staging: wave w stages rows [32w, 32w+32) of each [256][64] tile,
    // 4 instrs x 8 rows (128B/row). phys chunk (lane&7) holds logical
    // (lane&7)^(row&7), row&7 = lane>>3.
    const int srow = wid * 32 + (lane >> 3);
    const int sch  = ((lane & 7) ^ (lane >> 3)) * 8;
    const unsigned short* Ag = A  + (size_t)(m0 + srow) * Kstride + koff + sch;
    const unsigned short* Bg = Bt + (size_t)(n0 + srow) * Kstride + koff + sch;
    const size_t rstep8 = (size_t)8 * Kstride;
    unsigned short* Abase = &Ald[0][(wid * 32) * 64];
    unsigned short* Bbase = &Bld[0][(wid * 32) * 64];

    f32x4 acc[8][4] = {};
    short8 bfr[4];
    const int T = K >> 6;

#define STAGE_TILE(TT) do { const int b_ = (TT) & 1; const int c_ = (TT) * 64; \
        _Pragma("unroll")                                                      \
        for (int i_ = 0; i_ < 4; i_++) {                                       \
            async_load16(Ag + c_ + i_ * rstep8,                                \
                         Abase + b_ * 256 * 64 + i_ * 8 * 64);                 \
            async_load16(Bg + c_ + i_ * rstep8,                                \
                         Bbase + b_ * 256 * 64 + i_ * 8 * 64);                 \
        } } while (0)

#define PH(KH, MB, LOADB)                                                     \
    {                                                                         \
        short8 af_[4];                                                        \
        _Pragma("unroll")                                                     \
        for (int i_ = 0; i_ < 4; i_++)                                        \
            af_[i_] = *(const short8*)&Ald[cb][                               \
                (wm * 128 + ((MB) + i_) * 16 + lr) * 64 +                     \
                (((quad + (KH) * 4)) ^ (lr & 7)) * 8];                        \
        if (LOADB) {                                                          \
            _Pragma("unroll")                                                 \
            for (int i_ = 0; i_ < 4; i_++)                                    \
                bfr[i_] = *(const short8*)&Bld[cb][                           \
                    (wn * 64 + i_ * 16 + lr) * 64 +                           \
                    (((quad + (KH) * 4)) ^ (lr & 7)) * 8];                    \
        }                                                                     \
        __builtin_amdgcn_s_barrier();                                         \
        asm volatile("s_waitcnt lgkmcnt(0)" ::: "memory");                    \
        __builtin_amdgcn_sched_barrier(0);                                    \
        __builtin_amdgcn_s_setprio(1);                                        \
        _Pragma("unroll")                                                     \
        for (int mi_ = 0; mi_ < 4; mi_++)                                     \
            _Pragma("unroll")                                                 \
            for (int ni_ = 0; ni_ < 4; ni_++)                                 \
                acc[(MB) + mi_][ni_] = __builtin_amdgcn_mfma_f32_16x16x32_bf16( \
                    af_[mi_], bfr[ni_], acc[(MB) + mi_][ni_], 0, 0, 0);       \
        __builtin_amdgcn_s_setprio(0);                                        \
        __builtin_amdgcn_s_barrier();                                         \
    }

    // prologue: stage tiles 0 and 1 (16 loads/wave in flight)
    STAGE_TILE(0);
    STAGE_TILE(1);

    for (int kt = 0; kt < T; kt++) {
        const int cb = kt & 1;
        // publish tile kt: completes its 8 loads; leaves tile kt+1's 8.
        if (kt < T - 1) {
            asm volatile("s_waitcnt vmcnt(8)" ::: "memory");
        } else {
            asm volatile("s_waitcnt vmcnt(0)" ::: "memory");
        }
        __builtin_amdgcn_s_barrier();

        PH(0, 0, 1)
        PH(0, 4, 0)
        PH(1, 0, 1)
        PH(1, 4, 0)

        // stage tile kt+2 into buf[kt&1] (its readers just retired)
        if (kt + 2 < T) STAGE_TILE(kt + 2);
    }

#undef PH
#undef STAGE_TILE

    // epilogue
    const float QSC = 0.18033688011112042f;  // (1/8) * log2(e)
    float* pOut = (MODE == 5) ? outF + (size_t)blockIdx.z * M * N : outF;
#pragma unroll
    for (int mi = 0; mi < 8; mi++)
#pragma unroll
        for (int ni = 0; ni < 4; ni++) {
            const int col  = n0 + wn * 64 + ni * 16 + lr;
            const int row0 = m0 + wm * 128 + mi * 16 + quad * 4;
            if (MODE == 4 && col >= 2048) {
                // V portion: store transposed Vt[b][c][s], 4 consecutive s
                int bb = row0 >> 11, ss = row0 & 2047, c = col - 2048;
                ushort4 ov;
                ov.x = f2bf(acc[mi][ni][0]); ov.y = f2bf(acc[mi][ni][1]);
                ov.z = f2bf(acc[mi][ni][2]); ov.w = f2bf(acc[mi][ni][3]);
                *(ushort4*)&vtB[((size_t)bb * 1024 + c) * 2048 + ss] = ov;
            } else {
#pragma unroll
                for (int r = 0; r < 4; r++) {
                    size_t idx = (size_t)(row0 + r) * N + col;
                    float v = acc[mi][ni][r];
                    if (MODE == 4) {
                        outB[idx] = f2bf(col < 1024 ? v * QSC : v);
                    } else if (MODE == 2) {
                        v += bias[col];
                        outB[idx] = f2bf(v > 0.f ? v : 0.f);
                    } else if (MODE == 5) {
                        pOut[idx] = v;
                    }
                }
            }
        }
}

// ---------------------------------------------------------------------------
// Flash attention, S^T formulation, no online max (scores bounded).
// P kept fully in registers via permlane32_swap + permlane16_swap (round 7).
__global__ __launch_bounds__(256) void attention_kernel(
    const unsigned short* __restrict__ qkv, const unsigned short* __restrict__ Vt,
    unsigned short* __restrict__ ctx) {
    __shared__ unsigned short Kbuf[2][64 * 64];   // [key][hd], chunk-swizzled
    __shared__ unsigned short Vbuf[2][64 * 64];   // [hd][key], chunk-swizzled

    const int qt = blockIdx.x, h = blockIdx.y, b = blockIdx.z;
    const int t = threadIdx.x, wid = t >> 6, lane = t & 63;
    const int lr = lane & 15, quad = lane >> 4;
    const int q0 = qt * 64 + wid * 16;

    size_t qbase = ((size_t)(b * 2048 + q0 + lr)) * 3072 + h * 64;
    short8 qf0 = *(const short8*)(qkv + qbase + quad * 8);
    short8 qf1 = *(const short8*)(qkv + qbase + 32 + quad * 8);

    const int srow = wid * 8 + (lane >> 3);            // 0..31
    const int sch  = ((lane & 7) ^ (srow & 7)) * 8;    // fetch-side swizzle
    const unsigned short* Kg =
        qkv + (size_t)b * 2048 * 3072 + 1024 + h * 64 + (size_t)srow * 3072 + sch;
    const unsigned short* Vg =
        Vt + ((size_t)b * 1024 + h * 64 + srow) * 2048 + sch;
    unsigned short* KsB = (unsigned short*)&Kbuf[0][(wid * 8) * 64];
    unsigned short* VsB = (unsigned short*)&Vbuf[0][(wid * 8) * 64];
    const int bufstep = 64 * 64;

    short8 ones;
#pragma unroll
    for (int i = 0; i < 8; i++) ones[i] = (short)0x3F80;  // bf16 1.0

    f32x4 o[4] = {};
    f32x4 lacc = {};

#pragma unroll
    for (int half = 0; half < 2; half++) {
        async_load16(Kg + (size_t)(half * 32) * 3072, KsB + half * 32 * 64);
        async_load16(Vg + (size_t)(half * 32) * 2048, VsB + half * 32 * 64);
    }

    const int swz = lr & 7;

    for (int kt = 0; kt < 32; kt++) {
        const int cur = kt & 1, nxt = cur ^ 1;
        __syncthreads();
        if (kt + 1 < 32) {
#pragma unroll
            for (int half = 0; half < 2; half++) {
                async_load16(Kg + (size_t)((kt + 1) * 64 + half * 32) * 3072,
                             KsB + nxt * bufstep + half * 32 * 64);
                async_load16(Vg + (size_t)(half * 32) * 2048 + (kt + 1) * 64,
                             VsB + nxt * bufstep + half * 32 * 64);
            }
        }

        const unsigned short* Kc = &Kbuf[cur][0];
        const unsigned short* Vc = &Vbuf[cur][0];

        f32x4 s[4] = {};
#pragma unroll
        for (int nt = 0; nt < 4; nt++) {
            const unsigned short* krow = Kc + (nt * 16 + lr) * 64;
            short8 kf0 = *(const short8*)(krow + (quad ^ swz) * 8);
            short8 kf1 = *(const short8*)(krow + ((quad + 4) ^ swz) * 8);
            s[nt] = __builtin_amdgcn_mfma_f32_16x16x32_bf16(kf0, qf0, s[nt], 0, 0, 0);
            s[nt] = __builtin_amdgcn_mfma_f32_16x16x32_bf16(kf1, qf1, s[nt], 0, 0, 0);
        }

        // exp2 + pack into bf16x2 words; aw = keys (.,+1), bw = keys (+2,+3)
        unsigned int aw[4], bw[4];
#pragma unroll
        for (int nt = 0; nt < 4; nt++) {
            float p0 = __builtin_amdgcn_exp2f(s[nt][0]);
            float p1 = __builtin_amdgcn_exp2f(s[nt][1]);
            float p2 = __builtin_amdgcn_exp2f(s[nt][2]);
            float p3 = __builtin_amdgcn_exp2f(s[nt][3]);
            aw[nt] = pack_bf16_trunc(p0, p1);
            bw[nt] = pack_bf16_trunc(p2, p3);
        }

        // cross-quad redistribution, P stays in VGPRs
        uivec2 rA = __builtin_amdgcn_permlane32_swap(aw[0], aw[1], false, false);
        uivec2 sA = __builtin_amdgcn_permlane32_swap(aw[2], aw[3], false, false);
        uivec2 rB = __builtin_amdgcn_permlane32_swap(bw[0], bw[1], false, false);
        uivec2 sB = __builtin_amdgcn_permlane32_swap(bw[2], bw[3], false, false);
        uivec2 tA = __builtin_amdgcn_permlane16_swap(rA.x, rA.y, false, false);
        uivec2 uA = __builtin_amdgcn_permlane16_swap(sA.x, sA.y, false, false);
        uivec2 tB = __builtin_amdgcn_permlane16_swap(rB.x, rB.y, false, false);
        uivec2 uB = __builtin_amdgcn_permlane16_swap(sB.x, sB.y, false, false);

        union { unsigned int w[4]; short8 v; } P0, P1;
        P0.w[0] = tA.x; P0.w[1] = tB.x; P0.w[2] = tA.y; P0.w[3] = tB.y;
        P1.w[0] = uA.x; P1.w[1] = uB.x; P1.w[2] = uA.y; P1.w[3] = uB.y;
        short8 pf0 = P0.v;
        short8 pf1 = P1.v;

#pragma unroll
        for (int nt = 0; nt < 4; nt++) {
            const unsigned short* vrow = Vc + (nt * 16 + lr) * 64;
            short8 vf0 = *(const short8*)(vrow + (quad ^ swz) * 8);
            short8 vf1 = *(const short8*)(vrow + ((quad + 4) ^ swz) * 8);
            o[nt] = __builtin_amdgcn_mfma_f32_16x16x32_bf16(pf0, vf0, o[nt], 0, 0, 0);
            o[nt] = __builtin_amdgcn_mfma_f32_16x16x32_bf16(pf1, vf1, o[nt], 0, 0, 0);
        }
        lacc = __builtin_amdgcn_mfma_f32_16x16x32_bf16(pf0, ones, lacc, 0, 0, 0);
        lacc = __builtin_amdgcn_mfma_f32_16x16x32_bf16(pf1, ones, lacc, 0, 0, 0);
    }

#pragma unroll
    for (int r = 0; r < 4; r++) {
        float li = 1.f / lacc[r];
        int q = qt * 64 + wid * 16 + quad * 4 + r;
#pragma unroll
        for (int nt = 0; nt < 4; nt++)
            ctx[((size_t)(b * 2048 + q)) * 1024 + h * 64 + nt * 16 + lr] =
                f2bf(o[nt][r] * li);
    }
}

// ---------------------------------------------------------------------------
// LayerNorm over rows of 1024. OUTMODE 0: f32 out; 1: bf16 out.
template <int OUTMODE>
__global__ __launch_bounds__(256) void layernorm_kernel(
    const float* __restrict__ x, const float* __restrict__ g,
    const float* __restrict__ be, float* __restrict__ yF,
    unsigned short* __restrict__ yB) {
    const int row = blockIdx.x, t = threadIdx.x;
    const float* xr = x + (size_t)row * 1024;
    float4 v = *(const float4*)(xr + t * 4);
    float s  = v.x + v.y + v.z + v.w;
    float sq = v.x * v.x + v.y * v.y + v.z * v.z + v.w * v.w;
#pragma unroll
    for (int d = 1; d < 64; d <<= 1) {
        s  += __shfl_xor(s, d, 64);
        sq += __shfl_xor(sq, d, 64);
    }
    __shared__ float sh[8];
    int wid = t >> 6, lane = t & 63;
    if (lane == 0) { sh[wid] = s; sh[4 + wid] = sq; }
    __syncthreads();
    s  = sh[0] + sh[1] + sh[2] + sh[3];
    sq = sh[4] + sh[5] + sh[6] + sh[7];
    float mu  = s * (1.f / 1024.f);
    float var = sq * (1.f / 1024.f) - mu * mu;
    float rstd = rsqrtf(var + 1e-5f);
    float4 gv = *(const float4*)(g + t * 4);
    float4 bv = *(const float4*)(be + t * 4);
    float4 y;
    y.x = (v.x - mu) * rstd * gv.x + bv.x;
    y.y = (v.y - mu) * rstd * gv.y + bv.y;
    y.z = (v.z - mu) * rstd * gv.z + bv.z;
    y.w = (v.w - mu) * rstd * gv.w + bv.w;
    if (OUTMODE == 0) {
        *(float4*)(yF + (size_t)row * 1024 + t * 4) = y;
    } else {
        ushort4 o;
        o.x = f2bf(y.x); o.y = f2bf(y.y); o.z = f2bf(y.z); o.w = f2bf(y.w);
        *(ushort4*)(yB + (size_t)row * 1024 + t * 4) = o;
    }
}

// ---------------------------------------------------------------------------
// LN2 with fused split-K reduce: x = p0 + p1 + bias + bf16(res); f32 out.
__global__ __launch_bounds__(256) void layernorm_sum2_kernel(
    const float* __restrict__ p0, const float* __restrict__ p1,
    const float* __restrict__ bias, const unsigned short* __restrict__ res,
    const float* __restrict__ g, const float* __restrict__ be,
    float* __restrict__ out) {
    const int row = blockIdx.x, t = threadIdx.x;
    const size_t base = (size_t)row * 1024 + t * 4;
    float4 a = *(const float4*)(p0 + base);
    float4 b = *(const float4*)(p1 + base);
    float4 bi = *(const float4*)(bias + t * 4);
    ushort4 rb = *(const ushort4*)(res + base);
    float4 v;
    v.x = a.x + b.x + bi.x + bf2f(rb.x);
    v.y = a.y + b.y + bi.y + bf2f(rb.y);
    v.z = a.z + b.z + bi.z + bf2f(rb.z);
    v.w = a.w + b.w + bi.w + bf2f(rb.w);
    float s  = v.x + v.y + v.z + v.w;
    float sq = v.x * v.x + v.y * v.y + v.z * v.z + v.w * v.w;
#pragma unroll
    for (int d = 1; d < 64; d <<= 1) {
        s  += __shfl_xor(s, d, 64);
        sq += __shfl_xor(sq, d, 64);
    }
    __shared__ float sh[8];
    int wid = t >> 6, lane = t & 63;
    if (lane == 0) { sh[wid] = s; sh[4 + wid] = sq; }
    __syncthreads();
    s  = sh[0] + sh[1] + sh[2] + sh[3];
    sq = sh[4] + sh[5] + sh[6] + sh[7];
    float mu  = s * (1.f / 1024.f);
    float var = sq * (1.f / 1024.f) - mu * mu;
    float rstd = rsqrtf(var + 1e-5f);
    float4 gv = *(const float4*)(g + t * 4);
    float4 bv = *(const float4*)(be + t * 4);
    float4 y;
    y.x = (v.x - mu) * rstd * gv.x + bv.x;
    y.y = (v.y - mu) * rstd * gv.y + bv.y;
    y.z = (v.z - mu) * rstd * gv.z + bv.z;
    y.w = (v.w - mu) * rstd * gv.w + bv.w;
    *(float4*)(out + base) = y;
}

// ---------------------------------------------------------------------------
extern "C" void kernel_launch(void* const* d_in, const int* in_sizes, int n_in,
                              void* d_out, int out_size, void* d_ws, size_t ws_size,
                              hipStream_t stream) {
    const float* src  = (const float*)d_in[0];
    const float* Wqkv = (const float*)d_in[1];
    const float* Wout = (const float*)d_in[2];
    const float* W1   = (const float*)d_in[3];
    const float* b1   = (const float*)d_in[4];
    const float* W2   = (const float*)d_in[5];
    const float* b2   = (const float*)d_in[6];
    const float* g1   = (const float*)d_in[7];
    const float* be1  = (const float*)d_in[8];
    const float* g2   = (const float*)d_in[9];
    const float* be2  = (const float*)d_in[10];
    float* out = (float*)d_out;

    const size_t NT = 8192;  // tokens = 4*2048
    char* ws = (char*)d_ws;
    unsigned short* src_bf = (unsigned short*)ws; ws += NT * 1024 * 2;
    unsigned short* Wqkv_t = (unsigned short*)ws; ws += (size_t)3072 * 1024 * 2;
    unsigned short* Wout_t = (unsigned short*)ws; ws += (size_t)1024 * 1024 * 2;
    unsigned short* W1_t   = (unsigned short*)ws; ws += (size_t)4096 * 1024 * 2;
    unsigned short* W2_t   = (unsigned short*)ws; ws += (size_t)1024 * 4096 * 2;
    unsigned short* qkv_bf = (unsigned short*)ws; ws += NT * 3072 * 2;  // 48 MB
    unsigned short* ctx_bf = (unsigned short*)ws; ws += NT * 1024 * 2;  // 16 MB
    float*          x1     = (float*)ws;          ws += NT * 1024 * 4;  // 32 MB
    unsigned short* y1_bf  = (unsigned short*)ws; ws += NT * 1024 * 2;
    unsigned short* h_bf   = (unsigned short*)ws; ws += NT * 4096 * 2;
    // aliases over dead buffers:
    unsigned short* Vt = h_bf;      // Vt dead before GEMM3 writes h_bf
    // Split-K partials: 2 x 32 MB CONTIGUOUS in qkv_bf..ctx_bf (64 MB).
    float* part = (float*)qkv_bf;   // z=0 at +0, z=1 at +NT*1024 floats

    // pre-pass: casts + weight transposes
    cast_bf16_kernel<<<8192, 256, 0, stream>>>(src, src_bf);
    transpose_cast_kernel<<<dim3(96, 32), 256, 0, stream>>>(Wqkv, Wqkv_t, 1024, 3072);
    transpose_cast_kernel<<<dim3(32, 32), 256, 0, stream>>>(Wout, Wout_t, 1024, 1024);
    transpose_cast_kernel<<<dim3(128, 32), 256, 0, stream>>>(W1, W1_t, 1024, 4096);
    transpose_cast_kernel<<<dim3(32, 128), 256, 0, stream>>>(W2, W2_t, 4096, 1024);

    // qkv = src @ Wqkv  (Q scaled -> qkv_bf; K -> qkv_bf; V -> Vt transposed)
    gemm256_bf16_kernel<4><<<dim3(32, 12), 512, 0, stream>>>(
        src_bf, Wqkv_t, 8192, 3072, 1024, 1024,
        nullptr, qkv_bf, nullptr, nullptr, nullptr, Vt);
    // attention
    attention_kernel<<<dim3(32, 16, 4), 256, 0, stream>>>(qkv_bf, Vt, ctx_bf);
    // x1 = ctx @ Wout + src   (old 128x128 kernel: N=1024 tail-bound shape)
    gemm_bf16_kernel<1><<<dim3(64, 8), 256, 0, stream>>>(
        ctx_bf, Wout_t, 8192, 1024, 1024, 1024,
        x1, nullptr, nullptr, src, nullptr, nullptr);
    // y1 = LN1(x1)
    layernorm_kernel<1><<<8192, 256, 0, stream>>>(x1, g1, be1, nullptr, y1_bf);
    // h = relu(y1 @ W1 + b1)
    gemm256_bf16_kernel<2><<<dim3(32, 16), 512, 0, stream>>>(
        y1_bf, W1_t, 8192, 4096, 1024, 1024,
        nullptr, h_bf, b1, nullptr, nullptr, nullptr);
    // split-K x2: part[z] = h @ W2[zK:(z+1)K, :]   (z = blockIdx.z)
    gemm256_bf16_kernel<5><<<dim3(32, 4, 2), 512, 0, stream>>>(
        h_bf, W2_t, 8192, 1024, 2048, 4096,
        part, nullptr, nullptr, nullptr, nullptr, nullptr);
    // out = LN2(part0 + part1 + b2 + y1)
    layernorm_sum2_kernel<<<8192, 256, 0, stream>>>(
        part, part + NT * 1024, b2, y1_bf, g2, be2, out);
}

// Round 5
// 514.452 us; speedup vs baseline: 1.0560x; 1.0551x over previous
//
#include <hip/hip_runtime.h>
#include <hip/hip_bf16.h>

// ---------------------------------------------------------------------------
// Transformer encoder layer (post-norm), bf16 MFMA implementation.
// D=1024, H=16, HD=64, FF=4096, B=4, S=2048 -> 8192 tokens.
//
// Round 11 (= round-1 GEMM config + dual-Q attention):
//  - GEMMs reverted to the proven 128x128 kernel (two 256-tile attempts both
//    lost to it at these K=1024/2048 shapes; round-3 total +22us vs round-1).
//  - attention: QBLK 64 -> 128. Each wave owns 32 queries (two 16-row
//    fragments). K/V LDS fragments are read ONCE per wave and feed both
//    Q-fragments -> LDS read bytes/query HALVED (attention was LDS-read-BW
//    bound: 4 waves x 16KB/tile = 770cy/CU-tile ~= the measured 96us).
//    K/V HBM refetch also halves (1024 blocks instead of 2048).
//    In-register P via permlane swaps unchanged (per-fragment duplication).
// ---------------------------------------------------------------------------

typedef __attribute__((ext_vector_type(8))) short          short8;
typedef __attribute__((ext_vector_type(8))) unsigned short ushort8;
typedef __attribute__((ext_vector_type(4))) float          f32x4;
typedef __attribute__((ext_vector_type(2))) unsigned int   uivec2;

__device__ __forceinline__ unsigned short f2bf(float f) {
    union { float f; unsigned int u; } v; v.f = f;
    unsigned int u = v.u;
    unsigned int r = (u + 0x7fffu + ((u >> 16) & 1u)) >> 16;
    return (unsigned short)r;
}

__device__ __forceinline__ float bf2f(unsigned short u) {
    union { unsigned int u; float f; } v; v.u = ((unsigned int)u) << 16;
    return v.f;
}

// truncate-pack two f32 -> (bf16(hi)<<16)|bf16(lo)
__device__ __forceinline__ unsigned int pack_bf16_trunc(float lo, float hi) {
    union { float f; unsigned int u; } a, b; a.f = lo; b.f = hi;
    return __builtin_amdgcn_perm(b.u, a.u, 0x07060302u);  // {b.hi16, a.hi16}
}

// async global->LDS, 16 B per lane. LDS dest = wave-uniform base + lane*16.
__device__ __forceinline__ void async_load16(const void* g, void* l) {
    __builtin_amdgcn_global_load_lds(
        (const __attribute__((address_space(1))) void*)(unsigned long long)g,
        (__attribute__((address_space(3))) void*)(unsigned long long)l,
        16, 0, 0);
}

// exp2 of 16 scores (4x f32x4) -> two bf16x8 PV A-fragments, via
// permlane32_swap + permlane16_swap (round-7 verified mapping).
__device__ __forceinline__ void softmax_frag(const f32x4* s,
                                             short8& pf0, short8& pf1) {
    unsigned int aw[4], bw[4];
#pragma unroll
    for (int nt = 0; nt < 4; nt++) {
        float p0 = __builtin_amdgcn_exp2f(s[nt][0]);
        float p1 = __builtin_amdgcn_exp2f(s[nt][1]);
        float p2 = __builtin_amdgcn_exp2f(s[nt][2]);
        float p3 = __builtin_amdgcn_exp2f(s[nt][3]);
        aw[nt] = pack_bf16_trunc(p0, p1);
        bw[nt] = pack_bf16_trunc(p2, p3);
    }
    uivec2 rA = __builtin_amdgcn_permlane32_swap(aw[0], aw[1], false, false);
    uivec2 sA = __builtin_amdgcn_permlane32_swap(aw[2], aw[3], false, false);
    uivec2 rB = __builtin_amdgcn_permlane32_swap(bw[0], bw[1], false, false);
    uivec2 sB = __builtin_amdgcn_permlane32_swap(bw[2], bw[3], false, false);
    uivec2 tA = __builtin_amdgcn_permlane16_swap(rA.x, rA.y, false, false);
    uivec2 uA = __builtin_amdgcn_permlane16_swap(sA.x, sA.y, false, false);
    uivec2 tB = __builtin_amdgcn_permlane16_swap(rB.x, rB.y, false, false);
    uivec2 uB = __builtin_amdgcn_permlane16_swap(sB.x, sB.y, false, false);
    union { unsigned int w[4]; short8 v; } P0, P1;
    P0.w[0] = tA.x; P0.w[1] = tB.x; P0.w[2] = tA.y; P0.w[3] = tB.y;
    P1.w[0] = uA.x; P1.w[1] = uB.x; P1.w[2] = uA.y; P1.w[3] = uB.y;
    pf0 = P0.v;
    pf1 = P1.v;
}

// ---------------------------------------------------------------------------
// cast f32 -> bf16, 4 elems/thread
__global__ __launch_bounds__(256) void cast_bf16_kernel(
    const float* __restrict__ x, unsigned short* __restrict__ y) {
    size_t i = ((size_t)blockIdx.x * 256 + threadIdx.x) * 4;
    float4 v = *(const float4*)(x + i);
    ushort4 o; o.x = f2bf(v.x); o.y = f2bf(v.y); o.z = f2bf(v.z); o.w = f2bf(v.w);
    *(ushort4*)(y + i) = o;
}

// ---------------------------------------------------------------------------
// W [K,N] f32 row-major  ->  Wt [N,K] bf16 row-major
__global__ __launch_bounds__(256) void transpose_cast_kernel(
    const float* __restrict__ W, unsigned short* __restrict__ Wt, int K, int N) {
    __shared__ float tile[32][33];
    int n0 = blockIdx.x * 32, k0 = blockIdx.y * 32;
    int tx = threadIdx.x & 31, ty = threadIdx.x >> 5;
#pragma unroll
    for (int i = 0; i < 32; i += 8)
        tile[ty + i][tx] = W[(size_t)(k0 + ty + i) * N + n0 + tx];
    __syncthreads();
#pragma unroll
    for (int i = 0; i < 32; i += 8)
        Wt[(size_t)(n0 + ty + i) * K + k0 + tx] = f2bf(tile[tx][ty + i]);
}

// ---------------------------------------------------------------------------
// 128x128 GEMM (m97 structure), BK=32, 256 thr (4 waves 2x2), 16x16x32 MFMA.
// Double-buffered LDS, one barrier per K-iter, global_load_lds(16B) staging,
// fetch-side XOR chunk swizzle (phys chunk p holds logical p^(row&3)).
// MODE 0: bf16 out; 1: outF = acc + resF; 2: outB = bf16(relu(acc+bias));
// MODE 3: outF = acc + bias + float(resB);
// MODE 4: qkv: col<1024 -> bf16(v*log2e/8); 1024..2047 -> bf16; >=2048 -> vtB^T
// MODE 5: f32 partial to outF + z*M*N
template <int MODE>
__global__ __launch_bounds__(256) void gemm_bf16_kernel(
    const unsigned short* __restrict__ A, const unsigned short* __restrict__ Bt,
    int M, int N, int K, int Kstride,
    float* __restrict__ outF, unsigned short* __restrict__ outB,
    const float* __restrict__ bias,
    const float* __restrict__ resF, const unsigned short* __restrict__ resB,
    unsigned short* __restrict__ vtB) {
    __shared__ unsigned short As[2][128 * 32];
    __shared__ unsigned short Bs[2][128 * 32];

    const int t = threadIdx.x;
    const int m0 = blockIdx.x * 128, n0 = blockIdx.y * 128;
    const int koff = blockIdx.z * K;
    const int wid = t >> 6, lane = t & 63;
    const int wm = wid >> 1, wn = wid & 1;
    const int lr = lane & 15, quad = lane >> 4;

    const int srow = lane >> 2;                       // 0..15
    const int sch  = ((lane & 3) ^ (srow & 3)) * 8;   // swizzled logical chunk
    const unsigned short* Ag =
        A  + (size_t)(m0 + wid * 32 + srow) * Kstride + koff + sch;
    const unsigned short* Bg =
        Bt + (size_t)(n0 + wid * 32 + srow) * Kstride + koff + sch;
    const int wofs = (wid * 32) * 32;
    const size_t rstep = (size_t)16 * Kstride;

    const int axs = ((quad ^ (lr & 3))) * 8;          // phys chunk for reads
    f32x4 acc[4][4] = {};

    const int nK = K >> 5;
    // initial stage into buf 0
    async_load16(Ag,         &As[0][wofs]);
    async_load16(Ag + rstep, &As[0][wofs + 16 * 32]);
    async_load16(Bg,         &Bs[0][wofs]);
    async_load16(Bg + rstep, &Bs[0][wofs + 16 * 32]);

    for (int kt = 0; kt < nK; kt++) {
        const int cur = kt & 1, nxt = cur ^ 1;
        __syncthreads();   // drains own DMA (vmcnt) + prior LDS reads
        if (kt + 1 < nK) {
            const int k1 = (kt + 1) * 32;
            async_load16(Ag + k1,         &As[nxt][wofs]);
            async_load16(Ag + k1 + rstep, &As[nxt][wofs + 16 * 32]);
            async_load16(Bg + k1,         &Bs[nxt][wofs]);
            async_load16(Bg + k1 + rstep, &Bs[nxt][wofs + 16 * 32]);
        }

        short8 af[4], bfr[4];
#pragma unroll
        for (int i = 0; i < 4; i++) {
            af[i]  = *(const short8*)&As[cur][(wm * 64 + i * 16 + lr) * 32 + axs];
            bfr[i] = *(const short8*)&Bs[cur][(wn * 64 + i * 16 + lr) * 32 + axs];
        }
#pragma unroll
        for (int mi = 0; mi < 4; mi++)
#pragma unroll
            for (int ni = 0; ni < 4; ni++)
                acc[mi][ni] = __builtin_amdgcn_mfma_f32_16x16x32_bf16(
                    af[mi], bfr[ni], acc[mi][ni], 0, 0, 0);
    }

    const float QSC = 0.18033688011112042f;  // (1/8) * log2(e)
    float* pOut = (MODE == 5) ? outF + (size_t)blockIdx.z * M * N : outF;
#pragma unroll
    for (int mi = 0; mi < 4; mi++)
#pragma unroll
        for (int ni = 0; ni < 4; ni++) {
            const int col  = n0 + wn * 64 + ni * 16 + lr;
            const int row0 = m0 + wm * 64 + mi * 16 + quad * 4;
            if (MODE == 4 && col >= 2048) {
                // V portion: store transposed Vt[b][c][s], 4 consecutive s
                int bb = row0 >> 11, ss = row0 & 2047, c = col - 2048;
                ushort4 ov;
                ov.x = f2bf(acc[mi][ni][0]); ov.y = f2bf(acc[mi][ni][1]);
                ov.z = f2bf(acc[mi][ni][2]); ov.w = f2bf(acc[mi][ni][3]);
                *(ushort4*)&vtB[((size_t)bb * 1024 + c) * 2048 + ss] = ov;
            } else {
#pragma unroll
                for (int r = 0; r < 4; r++) {
                    size_t idx = (size_t)(row0 + r) * N + col;
                    float v = acc[mi][ni][r];
                    if (MODE == 4) {
                        outB[idx] = f2bf(col < 1024 ? v * QSC : v);
                    } else if (MODE == 0) {
                        outB[idx] = f2bf(v);
                    } else if (MODE == 1) {
                        outF[idx] = v + resF[idx];
                    } else if (MODE == 2) {
                        v += bias[col];
                        outB[idx] = f2bf(v > 0.f ? v : 0.f);
                    } else if (MODE == 3) {
                        outF[idx] = v + bias[col] + bf2f(resB[idx]);
                    } else {  // MODE 5
                        pOut[idx] = v;
                    }
                }
            }
        }
}

// ---------------------------------------------------------------------------
// Flash attention, S^T formulation, no online max (scores bounded).
// qkv bf16: [(b*2048+s)*3072 + comp*1024 + h*64 + hd]; Q pre-scaled by
// log2e/8, so p = exp2(mfma output). Vt bf16: [(b*1024+h*64+hd)*2048+s].
// DUAL-Q: QBLK=128, 4 waves, each wave owns 32 queries as two 16-row
// fragments (A: rows +0..15, B: rows +16..31). K/V LDS fragments are read
// once per wave and feed both fragments -> LDS bytes/query halved.
// P in registers via permlane swaps (softmax_frag).
__global__ __launch_bounds__(256, 4) void attention_kernel(
    const unsigned short* __restrict__ qkv, const unsigned short* __restrict__ Vt,
    unsigned short* __restrict__ ctx) {
    __shared__ unsigned short Kbuf[2][64 * 64];   // [key][hd], chunk-swizzled
    __shared__ unsigned short Vbuf[2][64 * 64];   // [hd][key], chunk-swizzled

    const int qt = blockIdx.x, h = blockIdx.y, b = blockIdx.z;
    const int t = threadIdx.x, wid = t >> 6, lane = t & 63;
    const int lr = lane & 15, quad = lane >> 4;
    const int q0 = qt * 128 + wid * 32;

    size_t qbaseA = ((size_t)(b * 2048 + q0 + lr)) * 3072 + h * 64;
    size_t qbaseB = ((size_t)(b * 2048 + q0 + 16 + lr)) * 3072 + h * 64;
    short8 qfA0 = *(const short8*)(qkv + qbaseA + quad * 8);
    short8 qfA1 = *(const short8*)(qkv + qbaseA + 32 + quad * 8);
    short8 qfB0 = *(const short8*)(qkv + qbaseB + quad * 8);
    short8 qfB1 = *(const short8*)(qkv + qbaseB + 32 + quad * 8);

    const int srow = wid * 8 + (lane >> 3);            // 0..31
    const int sch  = ((lane & 7) ^ (srow & 7)) * 8;    // fetch-side swizzle
    const unsigned short* Kg =
        qkv + (size_t)b * 2048 * 3072 + 1024 + h * 64 + (size_t)srow * 3072 + sch;
    const unsigned short* Vg =
        Vt + ((size_t)b * 1024 + h * 64 + srow) * 2048 + sch;
    unsigned short* KsB = (unsigned short*)&Kbuf[0][(wid * 8) * 64];
    unsigned short* VsB = (unsigned short*)&Vbuf[0][(wid * 8) * 64];
    const int bufstep = 64 * 64;

    short8 ones;
#pragma unroll
    for (int i = 0; i < 8; i++) ones[i] = (short)0x3F80;  // bf16 1.0

    f32x4 oA[4] = {}, oB[4] = {};
    f32x4 laccA = {}, laccB = {};

#pragma unroll
    for (int half = 0; half < 2; half++) {
        async_load16(Kg + (size_t)(half * 32) * 3072, KsB + half * 32 * 64);
        async_load16(Vg + (size_t)(half * 32) * 2048, VsB + half * 32 * 64);
    }

    const int swz = lr & 7;

    for (int kt = 0; kt < 32; kt++) {
        const int cur = kt & 1, nxt = cur ^ 1;
        __syncthreads();
        if (kt + 1 < 32) {
#pragma unroll
            for (int half = 0; half < 2; half++) {
                async_load16(Kg + (size_t)((kt + 1) * 64 + half * 32) * 3072,
                             KsB + nxt * bufstep + half * 32 * 64);
                async_load16(Vg + (size_t)(half * 32) * 2048 + (kt + 1) * 64,
                             VsB + nxt * bufstep + half * 32 * 64);
            }
        }

        const unsigned short* Kc = &Kbuf[cur][0];
        const unsigned short* Vc = &Vbuf[cur][0];

        f32x4 sA[4] = {}, sB[4] = {};
#pragma unroll
        for (int nt = 0; nt < 4; nt++) {
            const unsigned short* krow = Kc + (nt * 16 + lr) * 64;
            short8 kf0 = *(const short8*)(krow + (quad ^ swz) * 8);
            short8 kf1 = *(const short8*)(krow + ((quad + 4) ^ swz) * 8);
            sA[nt] = __builtin_amdgcn_mfma_f32_16x16x32_bf16(kf0, qfA0, sA[nt], 0, 0, 0);
            sA[nt] = __builtin_amdgcn_mfma_f32_16x16x32_bf16(kf1, qfA1, sA[nt], 0, 0, 0);
            sB[nt] = __builtin_amdgcn_mfma_f32_16x16x32_bf16(kf0, qfB0, sB[nt], 0, 0, 0);
            sB[nt] = __builtin_amdgcn_mfma_f32_16x16x32_bf16(kf1, qfB1, sB[nt], 0, 0, 0);
        }

        short8 pfA0, pfA1, pfB0, pfB1;
        softmax_frag(sA, pfA0, pfA1);
        softmax_frag(sB, pfB0, pfB1);

#pragma unroll
        for (int nt = 0; nt < 4; nt++) {
            const unsigned short* vrow = Vc + (nt * 16 + lr) * 64;
            short8 vf0 = *(const short8*)(vrow + (quad ^ swz) * 8);
            short8 vf1 = *(const short8*)(vrow + ((quad + 4) ^ swz) * 8);
            oA[nt] = __builtin_amdgcn_mfma_f32_16x16x32_bf16(pfA0, vf0, oA[nt], 0, 0, 0);
            oA[nt] = __builtin_amdgcn_mfma_f32_16x16x32_bf16(pfA1, vf1, oA[nt], 0, 0, 0);
            oB[nt] = __builtin_amdgcn_mfma_f32_16x16x32_bf16(pfB0, vf0, oB[nt], 0, 0, 0);
            oB[nt] = __builtin_amdgcn_mfma_f32_16x16x32_bf16(pfB1, vf1, oB[nt], 0, 0, 0);
        }
        laccA = __builtin_amdgcn_mfma_f32_16x16x32_bf16(pfA0, ones, laccA, 0, 0, 0);
        laccA = __builtin_amdgcn_mfma_f32_16x16x32_bf16(pfA1, ones, laccA, 0, 0, 0);
        laccB = __builtin_amdgcn_mfma_f32_16x16x32_bf16(pfB0, ones, laccB, 0, 0, 0);
        laccB = __builtin_amdgcn_mfma_f32_16x16x32_bf16(pfB1, ones, laccB, 0, 0, 0);
    }

#pragma unroll
    for (int r = 0; r < 4; r++) {
        float liA = 1.f / laccA[r];
        float liB = 1.f / laccB[r];
        int qA = q0 + quad * 4 + r;
        int qB = q0 + 16 + quad * 4 + r;
#pragma unroll
        for (int nt = 0; nt < 4; nt++) {
            ctx[((size_t)(b * 2048 + qA)) * 1024 + h * 64 + nt * 16 + lr] =
                f2bf(oA[nt][r] * liA);
            ctx[((size_t)(b * 2048 + qB)) * 1024 + h * 64 + nt * 16 + lr] =
                f2bf(oB[nt][r] * liB);
        }
    }
}

// ---------------------------------------------------------------------------
// LayerNorm over rows of 1024. OUTMODE 0: f32 out; 1: bf16 out.
template <int OUTMODE>
__global__ __launch_bounds__(256) void layernorm_kernel(
    const float* __restrict__ x, const float* __restrict__ g,
    const float* __restrict__ be, float* __restrict__ yF,
    unsigned short* __restrict__ yB) {
    const int row = blockIdx.x, t = threadIdx.x;
    const float* xr = x + (size_t)row * 1024;
    float4 v = *(const float4*)(xr + t * 4);
    float s  = v.x + v.y + v.z + v.w;
    float sq = v.x * v.x + v.y * v.y + v.z * v.z + v.w * v.w;
#pragma unroll
    for (int d = 1; d < 64; d <<= 1) {
        s  += __shfl_xor(s, d, 64);
        sq += __shfl_xor(sq, d, 64);
    }
    __shared__ float sh[8];
    int wid = t >> 6, lane = t & 63;
    if (lane == 0) { sh[wid] = s; sh[4 + wid] = sq; }
    __syncthreads();
    s  = sh[0] + sh[1] + sh[2] + sh[3];
    sq = sh[4] + sh[5] + sh[6] + sh[7];
    float mu  = s * (1.f / 1024.f);
    float var = sq * (1.f / 1024.f) - mu * mu;
    float rstd = rsqrtf(var + 1e-5f);
    float4 gv = *(const float4*)(g + t * 4);
    float4 bv = *(const float4*)(be + t * 4);
    float4 y;
    y.x = (v.x - mu) * rstd * gv.x + bv.x;
    y.y = (v.y - mu) * rstd * gv.y + bv.y;
    y.z = (v.z - mu) * rstd * gv.z + bv.z;
    y.w = (v.w - mu) * rstd * gv.w + bv.w;
    if (OUTMODE == 0) {
        *(float4*)(yF + (size_t)row * 1024 + t * 4) = y;
    } else {
        ushort4 o;
        o.x = f2bf(y.x); o.y = f2bf(y.y); o.z = f2bf(y.z); o.w = f2bf(y.w);
        *(ushort4*)(yB + (size_t)row * 1024 + t * 4) = o;
    }
}

// ---------------------------------------------------------------------------
// LN2 with fused split-K reduce: x = p0 + p1 + bias + bf16(res); f32 out.
__global__ __launch_bounds__(256) void layernorm_sum2_kernel(
    const float* __restrict__ p0, const float* __restrict__ p1,
    const float* __restrict__ bias, const unsigned short* __restrict__ res,
    const float* __restrict__ g, const float* __restrict__ be,
    float* __restrict__ out) {
    const int row = blockIdx.x, t = threadIdx.x;
    const size_t base = (size_t)row * 1024 + t * 4;
    float4 a = *(const float4*)(p0 + base);
    float4 b = *(const float4*)(p1 + base);
    float4 bi = *(const float4*)(bias + t * 4);
    ushort4 rb = *(const ushort4*)(res + base);
    float4 v;
    v.x = a.x + b.x + bi.x + bf2f(rb.x);
    v.y = a.y + b.y + bi.y + bf2f(rb.y);
    v.z = a.z + b.z + bi.z + bf2f(rb.z);
    v.w = a.w + b.w + bi.w + bf2f(rb.w);
    float s  = v.x + v.y + v.z + v.w;
    float sq = v.x * v.x + v.y * v.y + v.z * v.z + v.w * v.w;
#pragma unroll
    for (int d = 1; d < 64; d <<= 1) {
        s  += __shfl_xor(s, d, 64);
        sq += __shfl_xor(sq, d, 64);
    }
    __shared__ float sh[8];
    int wid = t >> 6, lane = t & 63;
    if (lane == 0) { sh[wid] = s; sh[4 + wid] = sq; }
    __syncthreads();
    s  = sh[0] + sh[1] + sh[2] + sh[3];
    sq = sh[4] + sh[5] + sh[6] + sh[7];
    float mu  = s * (1.f / 1024.f);
    float var = sq * (1.f / 1024.f) - mu * mu;
    float rstd = rsqrtf(var + 1e-5f);
    float4 gv = *(const float4*)(g + t * 4);
    float4 bv = *(const float4*)(be + t * 4);
    float4 y;
    y.x = (v.x - mu) * rstd * gv.x + bv.x;
    y.y = (v.y - mu) * rstd * gv.y + bv.y;
    y.z = (v.z - mu) * rstd * gv.z + bv.z;
    y.w = (v.w - mu) * rstd * gv.w + bv.w;
    *(float4*)(out + base) = y;
}

// ---------------------------------------------------------------------------
extern "C" void kernel_launch(void* const* d_in, const int* in_sizes, int n_in,
                              void* d_out, int out_size, void* d_ws, size_t ws_size,
                              hipStream_t stream) {
    const float* src  = (const float*)d_in[0];
    const float* Wqkv = (const float*)d_in[1];
    const float* Wout = (const float*)d_in[2];
    const float* W1   = (const float*)d_in[3];
    const float* b1   = (const float*)d_in[4];
    const float* W2   = (const float*)d_in[5];
    const float* b2   = (const float*)d_in[6];
    const float* g1   = (const float*)d_in[7];
    const float* be1  = (const float*)d_in[8];
    const float* g2   = (const float*)d_in[9];
    const float* be2  = (const float*)d_in[10];
    float* out = (float*)d_out;

    const size_t NT = 8192;  // tokens = 4*2048
    char* ws = (char*)d_ws;
    unsigned short* src_bf = (unsigned short*)ws; ws += NT * 1024 * 2;
    unsigned short* Wqkv_t = (unsigned short*)ws; ws += (size_t)3072 * 1024 * 2;
    unsigned short* Wout_t = (unsigned short*)ws; ws += (size_t)1024 * 1024 * 2;
    unsigned short* W1_t   = (unsigned short*)ws; ws += (size_t)4096 * 1024 * 2;
    unsigned short* W2_t   = (unsigned short*)ws; ws += (size_t)1024 * 4096 * 2;
    unsigned short* qkv_bf = (unsigned short*)ws; ws += NT * 3072 * 2;  // 48 MB
    unsigned short* ctx_bf = (unsigned short*)ws; ws += NT * 1024 * 2;  // 16 MB
    float*          x1     = (float*)ws;          ws += NT * 1024 * 4;  // 32 MB
    unsigned short* y1_bf  = (unsigned short*)ws; ws += NT * 1024 * 2;
    unsigned short* h_bf   = (unsigned short*)ws; ws += NT * 4096 * 2;
    // aliases over dead buffers:
    unsigned short* Vt = h_bf;      // Vt dead before GEMM3 writes h_bf
    // Split-K partials: 2 x 32 MB CONTIGUOUS in qkv_bf..ctx_bf (64 MB).
    float* part = (float*)qkv_bf;   // z=0 at +0, z=1 at +NT*1024 floats

    // pre-pass: casts + weight transposes
    cast_bf16_kernel<<<8192, 256, 0, stream>>>(src, src_bf);
    transpose_cast_kernel<<<dim3(96, 32), 256, 0, stream>>>(Wqkv, Wqkv_t, 1024, 3072);
    transpose_cast_kernel<<<dim3(32, 32), 256, 0, stream>>>(Wout, Wout_t, 1024, 1024);
    transpose_cast_kernel<<<dim3(128, 32), 256, 0, stream>>>(W1, W1_t, 1024, 4096);
    transpose_cast_kernel<<<dim3(32, 128), 256, 0, stream>>>(W2, W2_t, 4096, 1024);

    // qkv = src @ Wqkv  (Q scaled -> qkv_bf; K -> qkv_bf; V -> Vt transposed)
    gemm_bf16_kernel<4><<<dim3(64, 24), 256, 0, stream>>>(
        src_bf, Wqkv_t, 8192, 3072, 1024, 1024,
        nullptr, qkv_bf, nullptr, nullptr, nullptr, Vt);
    // attention (dual-Q: QBLK=128)
    attention_kernel<<<dim3(16, 16, 4), 256, 0, stream>>>(qkv_bf, Vt, ctx_bf);
    // x1 = ctx @ Wout + src
    gemm_bf16_kernel<1><<<dim3(64, 8), 256, 0, stream>>>(
        ctx_bf, Wout_t, 8192, 1024, 1024, 1024,
        x1, nullptr, nullptr, src, nullptr, nullptr);
    // y1 = LN1(x1)
    layernorm_kernel<1><<<8192, 256, 0, stream>>>(x1, g1, be1, nullptr, y1_bf);
    // h = relu(y1 @ W1 + b1)
    gemm_bf16_kernel<2><<<dim3(64, 32), 256, 0, stream>>>(
        y1_bf, W1_t, 8192, 4096, 1024, 1024,
        nullptr, h_bf, b1, nullptr, nullptr, nullptr);
    // split-K x2: part[z] = h @ W2[zK:(z+1)K, :]   (z = blockIdx.z)
    gemm_bf16_kernel<5><<<dim3(64, 8, 2), 256, 0, stream>>>(
        h_bf, W2_t, 8192, 1024, 2048, 4096,
        part, nullptr, nullptr, nullptr, nullptr, nullptr);
    // out = LN2(part0 + part1 + b2 + y1)
    layernorm_sum2_kernel<<<8192, 256, 0, stream>>>(
        part, part + NT * 1024, b2, y1_bf, g2, be2, out);
}